// Round 4
// baseline (155.972 us; speedup 1.0000x reference)
//
#include <hip/hip_runtime.h>

// 8192 rows x 64 cols complex. Row r: m = r & 63 (phase-A bits 0..5), h = r >> 6
// (phase-B bits 6..12). Gate angle[i] acts on row-bit (12-i).
// float4 element = (re,im) x 2 adjacent cols. One fused kernel, manual grid barrier.
// ws layout = phase-B LDS slot order (incl. swizzle): ws4[(oct*64+m)*512 + slotB(h,cb)].
#define PLANE (8192 * 64)
#define NBLK 512

__device__ __forceinline__ void gate_coeffs(float theta, float& a, float& s) {
    // truncated series, CUTOFF=10: a ~ cos(theta/2) thru t^10, s ~ sin(theta/2) thru t^9
    float t = 0.5f * theta;
    float u = t * t;
    s = t * (1.f + u * (-1.f/6.f + u * (1.f/120.f + u * (-1.f/5040.f + u * (1.f/362880.f)))));
    a = 1.f + u * (-0.5f + u * (1.f/24.f + u * (-1.f/720.f + u * (1.f/40320.f + u * (-1.f/3628800.f)))));
}

// v = (reA, imA, reB, imB) for two columns of one row; RX pair update.
__device__ __forceinline__ void bf(float4& v0, float4& v1, float a, float s) {
    float4 n0, n1;
    n0.x = a * v0.x + s * v1.y;  n0.y = a * v0.y - s * v1.x;
    n0.z = a * v0.z + s * v1.w;  n0.w = a * v0.w - s * v1.z;
    n1.x = a * v1.x + s * v0.y;  n1.y = a * v1.y - s * v0.x;
    n1.z = a * v1.z + s * v0.w;  n1.w = a * v1.w - s * v0.z;
    v0 = n0; v1 = n1;
}

// Bank-conflict-free LDS slot maps (bank-quad = slot % 8 for float4 slots).
// A: quad = cp ^ f(row), f bijective over any 8-row aligned group -> 8 lanes/quad.
__device__ __forceinline__ int slotA(int row, int cp) {
    return row * 8 + (cp ^ ((row ^ (row >> 3)) & 7));
}
// B: quad = ((h&1)<<2 | cp) ^ ((h>>1)&7) -> mixes h low bits across all 8 quads.
__device__ __forceinline__ int slotB(int h, int cp) {
    return (h * 4 + cp) ^ ((h >> 1) & 7);
}

__global__ __launch_bounds__(256, 2) void rx_fused(const float* __restrict__ xr,
                                                   const float* __restrict__ xi,
                                                   const float* __restrict__ angle,
                                                   float4* __restrict__ ws4,
                                                   unsigned int* __restrict__ cnt,
                                                   float* __restrict__ out) {
    __shared__ float4 l4[512];         // 8 KB, reused by both phases
    const int t = threadIdx.x, bid = blockIdx.x;

    float ca[13], sa[13];
    #pragma unroll
    for (int i = 0; i < 13; ++i) gate_coeffs(angle[i], ca[i], sa[i]);

    // ---------------- Phase A: row-bits 0..5 (rows g*64 .. g*64+63) ----------
    const int g = bid >> 2, qq = bid & 3;   // g = h (fixed), qq = 16-col quarter
    {
        const float4* xr4 = (const float4*)xr;
        const float4* xi4 = (const float4*)xi;
        int lr = t >> 2, c4 = t & 3;
        int ga = (g * 64 + lr) * 16 + qq * 4 + c4;
        float4 re = xr4[ga], im = xi4[ga];
        l4[slotA(lr, 2 * c4)]     = make_float4(re.x, im.x, re.y, im.y);
        l4[slotA(lr, 2 * c4 + 1)] = make_float4(re.z, im.z, re.w, im.w);
    }
    __syncthreads();

    {
        const int cp = t & 7, rp = t >> 3;  // 32 row-pairs x 8 col-pairs
        #pragma unroll
        for (int b = 0; b < 6; ++b) {
            int lo = ((rp >> b) << (b + 1)) | (rp & ((1 << b) - 1));
            int i0 = slotA(lo, cp), i1 = slotA(lo + (1 << b), cp);
            float4 v0 = l4[i0], v1 = l4[i1];
            bf(v0, v1, ca[12 - b], sa[12 - b]);
            l4[i0] = v0; l4[i1] = v1;
            __syncthreads();
        }
    }

    {   // write ws in phase-B slot order (64 B chunks per (oct,m))
        const int gg = (g >> 1) & 7;
        #pragma unroll
        for (int k = 0; k < 2; ++k) {
            int j = t + 256 * k;
            int m = j >> 3, cp8 = j & 7;
            int oct = qq * 2 + (cp8 >> 2), cb = cp8 & 3;
            ws4[(oct * 64 + m) * 512 + ((g * 4 + cb) ^ gg)] = l4[slotA(m, cp8)];
        }
    }

    // ---------------- Grid barrier (512 blocks co-resident by construction) --
    __threadfence();                    // per-wave: drain stores + L2 writeback
    __syncthreads();                    // all waves of this block flushed
    if (t == 0)
        __hip_atomic_fetch_add(cnt, 1u, __ATOMIC_RELEASE, __HIP_MEMORY_SCOPE_AGENT);
    while (__hip_atomic_load(cnt, __ATOMIC_RELAXED, __HIP_MEMORY_SCOPE_AGENT) < NBLK)
        __builtin_amdgcn_s_sleep(2);
    __threadfence();                    // acquire: invalidate so ws reads are fresh
    __syncthreads();

    // ---------------- Phase B: row-bits 6..12 (m fixed, h = 0..127) ----------
    const int m2 = bid >> 3, oc = bid & 7;  // oc = 8-col oct
    {
        const float4* src = ws4 + (size_t)(oc * 64 + m2) * 512;  // contiguous 8 KB
        typedef const __attribute__((address_space(1))) unsigned int* g32;
        typedef __attribute__((address_space(3))) unsigned int* l32;
        #pragma unroll
        for (int k = 0; k < 2; ++k) {
            int slot = t + 256 * k;     // linear LDS dest (swizzle baked into ws order)
            __builtin_amdgcn_global_load_lds((g32)(src + slot), (l32)(l4 + slot), 16, 0, 0);
        }
        asm volatile("s_waitcnt vmcnt(0)" ::: "memory");
    }
    __syncthreads();

    {
        const int cp = t & 3, hp = t >> 2;  // 64 h-pairs x 4 col-pairs
        #pragma unroll
        for (int q = 0; q < 7; ++q) {
            int h0 = ((hp >> q) << (q + 1)) | (hp & ((1 << q) - 1));
            int i0 = slotB(h0, cp), i1 = slotB(h0 + (1 << q), cp);
            float4 v0 = l4[i0], v1 = l4[i1];
            bf(v0, v1, ca[6 - q], sa[6 - q]);
            l4[i0] = v0; l4[i1] = v1;
            __syncthreads();
        }
    }

    {   // de-interleave + store: 16 B chunks per (h, plane)
        float4* or4 = (float4*)out;
        float4* oi4 = (float4*)(out + PLANE);
        #pragma unroll
        for (int k = 0; k < 2; ++k) {
            int j = t + 256 * k;
            int h = j >> 2, c = (j >> 1) & 1, pl = j & 1;
            float4 v0 = l4[slotB(h, 2 * c)];
            float4 v1 = l4[slotB(h, 2 * c + 1)];
            float4 val = pl ? make_float4(v0.y, v0.w, v1.y, v1.w)
                            : make_float4(v0.x, v0.z, v1.x, v1.z);
            (pl ? oi4 : or4)[(h * 64 + m2) * 16 + oc * 2 + c] = val;
        }
    }
}

extern "C" void kernel_launch(void* const* d_in, const int* in_sizes, int n_in,
                              void* d_out, int out_size, void* d_ws, size_t ws_size,
                              hipStream_t stream) {
    const float* xr    = (const float*)d_in[0];
    const float* xi    = (const float*)d_in[1];
    const float* angle = (const float*)d_in[2];
    float*  out = (float*)d_out;
    float4* ws4 = (float4*)d_ws;                                  // 4 MB intermediate
    unsigned int* cnt = (unsigned int*)((char*)d_ws + (4u << 20)); // barrier counter

    hipMemsetAsync(cnt, 0, sizeof(unsigned int), stream);         // reset each replay
    rx_fused<<<NBLK, 256, 0, stream>>>(xr, xi, angle, ws4, cnt, out);
}

// Round 5
// 134.597 us; speedup vs baseline: 1.1588x; 1.1588x over previous
//
#include <hip/hip_runtime.h>

// 8192 rows x 64 cols complex, separate re/im float planes; out = [2][8192][64].
// Row r: m = r & 63 (phase A), h = r >> 6 (phase B). Gate angle[i] acts on row-bit (12-i).
// float4 element = (re,im) x 2 adjacent cols. Single fused kernel, manual grid barrier.
// ws layout = phase-B load order: ws4[bidB*512 + tB*2 + k], bidB = m*8+oct,
// tB = cB*64 + (h&63), k = h>>6  -> B wave reads 2KB contiguous.
#define PLANE (8192 * 64)
#define NBLK 512

__device__ __forceinline__ void gate_coeffs(float theta, float& a, float& s) {
    // truncated series, CUTOFF=10: a ~ cos(theta/2) thru t^10, s ~ sin(theta/2) thru t^9
    float t = 0.5f * theta;
    float u = t * t;
    s = t * (1.f + u * (-1.f/6.f + u * (1.f/120.f + u * (-1.f/5040.f + u * (1.f/362880.f)))));
    a = 1.f + u * (-0.5f + u * (1.f/24.f + u * (-1.f/720.f + u * (1.f/40320.f + u * (-1.f/3628800.f)))));
}

// v = (reA, imA, reB, imB) for two columns of one row; RX pair update.
__device__ __forceinline__ void bf(float4& v0, float4& v1, float a, float s) {
    float4 n0, n1;
    n0.x = a * v0.x + s * v1.y;  n0.y = a * v0.y - s * v1.x;
    n0.z = a * v0.z + s * v1.w;  n0.w = a * v0.w - s * v1.z;
    n1.x = a * v1.x + s * v0.y;  n1.y = a * v1.y - s * v0.x;
    n1.z = a * v1.z + s * v0.w;  n1.w = a * v1.w - s * v0.z;
    v0 = n0; v1 = n1;
}

// Phase-B LDS slot map: puts (h&1) into the bank-quad field and XORs with (h>>1)
// -> verified 8 lanes/quad for the load-writes, all sweep strides, final reads.
__device__ __forceinline__ int slotB(int h, int c) {
    return ((h >> 1) << 3) + (((((h & 1) << 2) | c) ^ (h >> 1)) & 7);
}

__global__ __launch_bounds__(256, 2) void rx_fused(const float* __restrict__ xr,
                                                   const float* __restrict__ xi,
                                                   const float* __restrict__ angle,
                                                   float4* __restrict__ ws4,
                                                   unsigned int* __restrict__ cnt,
                                                   float* __restrict__ out) {
    __shared__ float4 l4[512];         // 8 KB, reused by both phases
    const int t = threadIdx.x, bid = blockIdx.x;

    // ---------------- Phase A: row-bits 0..5; rows g*64..+63, cols CP = qa*8+cp8
    {
        const int g = bid >> 2, qa = bid & 3;
        const int rp = t >> 3, cp8 = t & 7;       // rp 0..31
        const int CP = qa * 8 + cp8;
        const float2* xr2 = (const float2*)xr;
        const float2* xi2 = (const float2*)xi;
        const int re_base = (g * 64 + 2 * rp) * 32 + CP;
        float2 re_e = xr2[re_base],      im_e = xi2[re_base];
        float2 re_o = xr2[re_base + 32], im_o = xi2[re_base + 32];

        float a0, s0; gate_coeffs(angle[12], a0, s0);         // bit 0, in regs
        float4 ve = make_float4(re_e.x, im_e.x, re_e.y, im_e.y);
        float4 vo = make_float4(re_o.x, im_o.x, re_o.y, im_o.y);
        bf(ve, vo, a0, s0);
        l4[(2 * rp) * 8 + cp8]     = ve;
        l4[(2 * rp + 1) * 8 + cp8] = vo;
        __syncthreads();

        #pragma unroll
        for (int b = 1; b <= 4; ++b) {                        // bits 1..4 in LDS
            float a, s; gate_coeffs(angle[12 - b], a, s);
            int lo = ((rp >> b) << (b + 1)) | (rp & ((1 << b) - 1));
            int i0 = lo * 8 + cp8, i1 = i0 + (8 << b);
            float4 v0 = l4[i0], v1 = l4[i1];
            bf(v0, v1, a, s);
            l4[i0] = v0; l4[i1] = v1;
            __syncthreads();
        }

        float a5, s5; gate_coeffs(angle[7], a5, s5);          // bit 5 + ws write
        float4 v0 = l4[rp * 8 + cp8], v1 = l4[(rp + 32) * 8 + cp8];
        bf(v0, v1, a5, s5);
        const int oct = CP >> 2, cB = CP & 3;
        const int ent = (cB * 64 + (g & 63)) * 2 + (g >> 6);
        ws4[(size_t)(rp * 8 + oct) * 512 + ent]        = v0;
        ws4[(size_t)((rp + 32) * 8 + oct) * 512 + ent] = v1;
    }

    // ---------------- Grid barrier: release -> count -> t0-only spin -> acquire
    __threadfence();                    // drain + L2 writeback (release side)
    __syncthreads();
    if (t == 0) {
        __hip_atomic_fetch_add(cnt, 1u, __ATOMIC_RELEASE, __HIP_MEMORY_SCOPE_AGENT);
        while (__hip_atomic_load(cnt, __ATOMIC_RELAXED, __HIP_MEMORY_SCOPE_AGENT) < NBLK)
            __builtin_amdgcn_s_sleep(8);
    }
    __syncthreads();
    __threadfence();                    // invalidate (acquire side)

    // ---------------- Phase B: row-bits 6..12; m fixed, h = 0..127, CP = oct*4+cB
    {
        const int m = bid >> 3, oct = bid & 7;
        const int h = t & 63, cB = t >> 6;
        const float4* src = ws4 + (size_t)bid * 512;
        float4 w0 = src[t * 2], w1 = src[t * 2 + 1];          // 32B/thread contiguous

        float a6, s6; gate_coeffs(angle[0], a6, s6);          // bit 12, in regs
        bf(w0, w1, a6, s6);
        l4[slotB(h, cB)]      = w0;
        l4[slotB(h + 64, cB)] = w1;
        __syncthreads();

        const int cB2 = t & 3, hp = t >> 2;                   // hp 0..63
        #pragma unroll
        for (int q = 1; q <= 5; ++q) {                        // bits 7..11 in LDS
            float a, s; gate_coeffs(angle[6 - q], a, s);
            int h0 = ((hp >> q) << (q + 1)) | (hp & ((1 << q) - 1));
            int i0 = slotB(h0, cB2), i1 = slotB(h0 + (1 << q), cB2);
            float4 v0 = l4[i0], v1 = l4[i1];
            bf(v0, v1, a, s);
            l4[i0] = v0; l4[i1] = v1;
            __syncthreads();
        }

        float a7, s7; gate_coeffs(angle[6], a7, s7);          // bit 6 + store
        float4 v0 = l4[slotB(2 * hp, cB2)], v1 = l4[slotB(2 * hp + 1, cB2)];
        bf(v0, v1, a7, s7);
        float2* outre2 = (float2*)out;
        float2* outim2 = (float2*)(out + PLANE);
        const int CP = oct * 4 + cB2;
        const int r0 = ((2 * hp) << 6) | m;                   // r1 = r0 + 64
        outre2[r0 * 32 + CP]        = make_float2(v0.x, v0.z);
        outim2[r0 * 32 + CP]        = make_float2(v0.y, v0.w);
        outre2[(r0 + 64) * 32 + CP] = make_float2(v1.x, v1.z);
        outim2[(r0 + 64) * 32 + CP] = make_float2(v1.y, v1.w);
    }
}

extern "C" void kernel_launch(void* const* d_in, const int* in_sizes, int n_in,
                              void* d_out, int out_size, void* d_ws, size_t ws_size,
                              hipStream_t stream) {
    const float* xr    = (const float*)d_in[0];
    const float* xi    = (const float*)d_in[1];
    const float* angle = (const float*)d_in[2];
    float*  out = (float*)d_out;
    float4* ws4 = (float4*)d_ws;                                   // 4 MB intermediate
    unsigned int* cnt = (unsigned int*)((char*)d_ws + (4u << 20)); // barrier counter

    hipMemsetAsync(cnt, 0, sizeof(unsigned int), stream);          // reset each replay
    rx_fused<<<NBLK, 256, 0, stream>>>(xr, xi, angle, ws4, cnt, out);
}

// Round 6
// 25.305 us; speedup vs baseline: 6.1637x; 5.3190x over previous
//
#include <hip/hip_runtime.h>

// 8192 rows x 64 cols complex, separate re/im float planes; out = [2][8192][64].
// Row r = h*64 + m. Gate angle[i] acts on row-bit (12-i).
// Phase A: r-bits 0..5 (within 64-row group, g = h fixed).
// Phase B: r-bits 6..12 (m fixed). Single kernel; barrier = relaxed atomics +
// per-access-coherent (sc0 sc1) ws stores/loads -> NO cache-maintenance fences.
// ws layout (A-natural): ws4[(g*4 + qa)*512 + m*8 + cp8], cp8 = col-pair within
// qa's 16 cols. A stores coalesced (1KB/wave); B gathers 64B chunks.
#define PLANE (8192 * 64)
#define NBLK 512

typedef float f4 __attribute__((ext_vector_type(4)));

__device__ __forceinline__ void gate_coeffs(float theta, float& a, float& s) {
    // truncated series, CUTOFF=10: a ~ cos(theta/2) thru t^10, s ~ sin(theta/2) thru t^9
    float t = 0.5f * theta;
    float u = t * t;
    s = t * (1.f + u * (-1.f/6.f + u * (1.f/120.f + u * (-1.f/5040.f + u * (1.f/362880.f)))));
    a = 1.f + u * (-0.5f + u * (1.f/24.f + u * (-1.f/720.f + u * (1.f/40320.f + u * (-1.f/3628800.f)))));
}

// v = (reA, imA, reB, imB) for two cols of one row; RX pair update.
__device__ __forceinline__ void bf(f4& v0, f4& v1, float a, float s) {
    f4 n0, n1;
    n0.x = a * v0.x + s * v1.y;  n0.y = a * v0.y - s * v1.x;
    n0.z = a * v0.z + s * v1.w;  n0.w = a * v0.w - s * v1.z;
    n1.x = a * v1.x + s * v0.y;  n1.y = a * v1.y - s * v0.x;
    n1.z = a * v1.z + s * v0.w;  n1.w = a * v1.w - s * v0.z;
    v0 = n0; v1 = n1;
}

// LDS slot maps, verified 8 lanes/bank-quad for every access pattern used.
__device__ __forceinline__ int slotA(int row, int c) {
    return row * 8 + (c ^ (row & 7));
}
__device__ __forceinline__ int slotB(int h, int c) {
    return ((h >> 1) << 3) + (((((h & 1) << 2) | c) ^ (h >> 1)) & 7);
}

__global__ __launch_bounds__(256, 2) void rx_fused(const float* __restrict__ xr,
                                                   const float* __restrict__ xi,
                                                   const float* __restrict__ angle,
                                                   f4* __restrict__ ws4,
                                                   unsigned int* __restrict__ cnt,
                                                   float* __restrict__ out) {
    __shared__ f4 l4[512];             // 8 KB, reused by both phases
    const int t = threadIdx.x, bid = blockIdx.x;

    // ---------------- Phase A: r-bits 0..5; rows g*64..+63, cols qa*16..+15 ---
    {
        const int g = bid >> 2, qa = bid & 3;
        const int row = t >> 2, c4 = t & 3;           // 1 row x 4 cols per thread
        const f4* xr4 = (const f4*)xr;
        const f4* xi4 = (const f4*)xi;
        int ga = (g * 64 + row) * 16 + qa * 4 + c4;
        f4 re = xr4[ga], im = xi4[ga];
        l4[slotA(row, 2 * c4)]     = (f4){re.x, im.x, re.y, im.y};
        l4[slotA(row, 2 * c4 + 1)] = (f4){re.z, im.z, re.w, im.w};
        __syncthreads();

        const int cp8 = t & 7, rp = t >> 3;           // 32 row-pairs x 8 col-pairs
        #pragma unroll
        for (int b = 0; b <= 4; ++b) {                // bits 0..4 in LDS
            float a, s; gate_coeffs(angle[12 - b], a, s);
            int lo = ((rp >> b) << (b + 1)) | (rp & ((1 << b) - 1));
            int i0 = slotA(lo, cp8), i1 = slotA(lo + (1 << b), cp8);
            f4 v0 = l4[i0], v1 = l4[i1];
            bf(v0, v1, a, s);
            l4[i0] = v0; l4[i1] = v1;
            __syncthreads();
        }

        float a5, s5; gate_coeffs(angle[7], a5, s5);  // bit 5, fused into ws store
        f4 v0 = l4[slotA(rp, cp8)], v1 = l4[slotA(rp + 32, cp8)];
        bf(v0, v1, a5, s5);
        const f4* wp0 = ws4 + ((size_t)(g * 4 + qa) * 512 + rp * 8 + cp8); // m=rp
        const f4* wp1 = wp0 + 256;                                          // m=rp+32
        asm volatile("global_store_dwordx4 %0, %1, off sc0 sc1\n\t"
                     "global_store_dwordx4 %2, %3, off sc0 sc1"
                     :: "v"(wp0), "v"(v0), "v"(wp1), "v"(v1) : "memory");
    }

    // ---------------- Barrier: vmcnt-drain release + relaxed striped atomics --
    asm volatile("s_waitcnt vmcnt(0)" ::: "memory");  // sc1 stores now agent-visible
    __syncthreads();
    if (t == 0) {
        __hip_atomic_fetch_add(cnt + (bid & 7) * 16, 1u,
                               __ATOMIC_RELAXED, __HIP_MEMORY_SCOPE_AGENT);
        unsigned int sum;
        do {
            __builtin_amdgcn_s_sleep(8);
            sum = 0;
            #pragma unroll
            for (int i = 0; i < 8; ++i)
                sum += __hip_atomic_load(cnt + i * 16,
                                         __ATOMIC_RELAXED, __HIP_MEMORY_SCOPE_AGENT);
        } while (sum < NBLK);
    }
    __syncthreads();                    // no acquire flush needed: B loads are sc0 sc1

    // ---------------- Phase B: r-bits 6..12; m fixed, h = 0..127 --------------
    {
        const int m2 = bid >> 3, oct = bid & 7;
        const int qa = oct >> 1, ch = oct & 1;        // qa's 16 cols, ch = which half
        const int hh = t >> 1, cc0 = (t & 1) * 2;
        const f4* rp0 = ws4 + ((size_t)(hh * 4 + qa) * 512 + m2 * 8 + ch * 4 + cc0);
        f4 w0, w1;
        asm volatile("global_load_dwordx4 %0, %2, off sc0 sc1\n\t"
                     "global_load_dwordx4 %1, %3, off sc0 sc1\n\t"
                     "s_waitcnt vmcnt(0)"
                     : "=&v"(w0), "=&v"(w1)
                     : "v"(rp0), "v"(rp0 + 1)
                     : "memory");
        l4[slotB(hh, cc0)]     = w0;
        l4[slotB(hh, cc0 + 1)] = w1;
        __syncthreads();

        const int cB = t & 3, hp = t >> 2;            // 64 h-pairs x 4 col-pairs
        #pragma unroll
        for (int q = 1; q <= 6; ++q) {                // r-bits 7..12 in LDS
            float a, s; gate_coeffs(angle[6 - q], a, s);
            int h0 = ((hp >> q) << (q + 1)) | (hp & ((1 << q) - 1));
            int i0 = slotB(h0, cB), i1 = slotB(h0 + (1 << q), cB);
            f4 v0 = l4[i0], v1 = l4[i1];
            bf(v0, v1, a, s);
            l4[i0] = v0; l4[i1] = v1;
            __syncthreads();
        }

        float a6, s6; gate_coeffs(angle[6], a6, s6);  // bit 6, fused into store
        f4 v0 = l4[slotB(2 * hp, cB)], v1 = l4[slotB(2 * hp + 1, cB)];
        bf(v0, v1, a6, s6);
        float2* outre2 = (float2*)out;
        float2* outim2 = (float2*)(out + PLANE);
        const int CP = oct * 4 + cB;
        const int r0 = (2 * hp) * 64 + m2;            // partner row = r0 + 64
        outre2[r0 * 32 + CP]        = make_float2(v0.x, v0.z);
        outim2[r0 * 32 + CP]        = make_float2(v0.y, v0.w);
        outre2[(r0 + 64) * 32 + CP] = make_float2(v1.x, v1.z);
        outim2[(r0 + 64) * 32 + CP] = make_float2(v1.y, v1.w);
    }
}

extern "C" void kernel_launch(void* const* d_in, const int* in_sizes, int n_in,
                              void* d_out, int out_size, void* d_ws, size_t ws_size,
                              hipStream_t stream) {
    const float* xr    = (const float*)d_in[0];
    const float* xi    = (const float*)d_in[1];
    const float* angle = (const float*)d_in[2];
    float* out = (float*)d_out;
    f4*    ws4 = (f4*)d_ws;                                        // 4 MB intermediate
    unsigned int* cnt = (unsigned int*)((char*)d_ws + (4u << 20)); // 8 striped counters

    hipMemsetAsync(cnt, 0, 512, stream);                           // reset each replay
    rx_fused<<<NBLK, 256, 0, stream>>>(xr, xi, angle, ws4, cnt, out);
}

// Round 8
// 14.730 us; speedup vs baseline: 10.5885x; 1.7179x over previous
//
#include <hip/hip_runtime.h>

// 8192 rows x 64 cols complex, separate re/im float planes; out = [2][8192][64].
// Row r = h*64 + m (h = r>>6, m = r&63). Gate angle[i] acts on row-bit (12-i).
// Kernel A: row-bits 0..5 (m-bits, h fixed per block).
// Kernel B: row-bits 6..12 (h-bits, m fixed per block).
// f4 element = (re,im) x 2 adjacent cols. Col-pair CP = 0..31, oct = CP>>2, c = CP&3.
// ws layout = B's swizzled LDS slot order: ws4[(m*8+oct)*512 + sB(h,c)]
//   -> A scatters 64B chunks; B reads 1KB/wave contiguous regions.
#define PLANE (8192 * 64)

typedef float f4 __attribute__((ext_vector_type(4)));

__device__ __forceinline__ void gate_coeffs(float theta, float& a, float& s) {
    // truncated series, CUTOFF=10: a ~ cos(theta/2) thru t^10, s ~ sin(theta/2) thru t^9
    float t = 0.5f * theta;
    float u = t * t;
    s = t * (1.f + u * (-1.f/6.f + u * (1.f/120.f + u * (-1.f/5040.f + u * (1.f/362880.f)))));
    a = 1.f + u * (-0.5f + u * (1.f/24.f + u * (-1.f/720.f + u * (1.f/40320.f + u * (-1.f/3628800.f)))));
}

// v = (reA, imA, reB, imB) for two cols of one row; RX pair update.
__device__ __forceinline__ void bf(f4& v0, f4& v1, float a, float s) {
    f4 n0, n1;
    n0.x = a * v0.x + s * v1.y;  n0.y = a * v0.y - s * v1.x;
    n0.z = a * v0.z + s * v1.w;  n0.w = a * v0.w - s * v1.z;
    n1.x = a * v1.x + s * v0.y;  n1.y = a * v1.y - s * v0.x;
    n1.z = a * v1.z + s * v0.w;  n1.w = a * v1.w - s * v0.z;
    v0 = n0; v1 = n1;
}

// LDS slot maps (f4 slots; bank-quad = slot & 7). Verified 8 distinct quads per
// 8-lane group for every access pattern used below.
__device__ __forceinline__ int slotA(int row, int c) {   // A: 64 rows x 8 col-pairs
    return row * 8 + (c ^ (row & 7));
}
__device__ __forceinline__ int sB(int h, int c) {        // B: 128 h x 4 col-pairs
    return ((h >> 1) << 3) | (((((h & 1) << 2) | c) ^ (h >> 1)) & 7);
}

// Kernel A: row-bits 0..4 in LDS, bit 5 fused into ws store.
// Block (g = h 0..127, qa = 16-col quarter). grid 512 x 256.
__global__ __launch_bounds__(256) void rx_low(const float* __restrict__ xr,
                                              const float* __restrict__ xi,
                                              const float* __restrict__ angle,
                                              f4* __restrict__ ws4) {
    __shared__ f4 la[512];             // 8 KB
    const int t = threadIdx.x, bid = blockIdx.x;
    const int g = bid >> 2, qa = bid & 3;

    {   // coalesced load (64B/4-lane-group), interleave re/im into LDS
        const int row = t >> 2, c4 = t & 3;
        const f4* xr4 = (const f4*)xr;
        const f4* xi4 = (const f4*)xi;
        int ga = (g * 64 + row) * 16 + qa * 4 + c4;
        f4 re = xr4[ga], im = xi4[ga];
        la[slotA(row, 2 * c4)]     = (f4){re.x, im.x, re.y, im.y};
        la[slotA(row, 2 * c4 + 1)] = (f4){re.z, im.z, re.w, im.w};
    }
    __syncthreads();

    const int cp8 = t & 7, rp = t >> 3;   // 32 row-pairs x 8 col-pairs
    #pragma unroll
    for (int b = 0; b <= 4; ++b) {        // bits 0..4
        float a, s; gate_coeffs(angle[12 - b], a, s);
        int lo = ((rp >> b) << (b + 1)) | (rp & ((1 << b) - 1));
        int i0 = slotA(lo, cp8), i1 = slotA(lo + (1 << b), cp8);
        f4 v0 = la[i0], v1 = la[i1];
        bf(v0, v1, a, s);
        la[i0] = v0; la[i1] = v1;
        __syncthreads();
    }

    // bit 5 in registers (pairs (rp, rp+32) — bit 5 IS the MSB of the 64-range)
    // + scatter store in B's slot order (16B chunks within 128B lines)
    float a5, s5; gate_coeffs(angle[7], a5, s5);
    f4 v0 = la[slotA(rp, cp8)], v1 = la[slotA(rp + 32, cp8)];
    bf(v0, v1, a5, s5);
    const int oct = qa * 2 + (cp8 >> 2), c = cp8 & 3;
    const int e = sB(g, c);
    ws4[(size_t)(rp * 8 + oct) * 512 + e]        = v0;   // m = rp
    ws4[(size_t)((rp + 32) * 8 + oct) * 512 + e] = v1;   // m = rp + 32
}

// Kernel B: h-bit 6 fused into load (MSB pairing), h-bits 0..4 in LDS,
// h-bit 5 fused into store (insert-zero pairing!).
// Block (m 0..63, oct 0..7). grid 512 x 256. Reads its 8KB ws slab contiguously.
__global__ __launch_bounds__(256) void rx_high(const float* __restrict__ angle,
                                               const f4* __restrict__ ws4,
                                               float* __restrict__ out) {
    __shared__ f4 lb[512];             // 8 KB
    const int t = threadIdx.x, bid = blockIdx.x;
    const int m = bid >> 3, oct = bid & 7;

    {   // contiguous 1KB/wave load regions; h-bit 6 (angle[0]) butterflied in regs
        const int hh = t >> 2, cL = t & 3;
        const f4* src = ws4 + (size_t)bid * 512;
        f4 w0 = src[sB(hh, cL)];       // slots 0..255 over the block
        f4 w1 = src[sB(hh + 64, cL)];  // slots 256..511 (h-bit 6 = MSB: pairing ok)
        float a6, s6; gate_coeffs(angle[0], a6, s6);
        bf(w0, w1, a6, s6);
        lb[sB(hh, cL)]      = w0;
        lb[sB(hh + 64, cL)] = w1;
    }
    __syncthreads();

    {   // h-bit 0 (stride 1, angle[6]) — dedicated mapping to stay conflict-free
        const int hp = t & 63, cL = t >> 6;
        float a, s; gate_coeffs(angle[6], a, s);
        int i0 = sB(2 * hp, cL), i1 = sB(2 * hp + 1, cL);
        f4 v0 = lb[i0], v1 = lb[i1];
        bf(v0, v1, a, s);
        lb[i0] = v0; lb[i1] = v1;
    }
    __syncthreads();

    const int cB = t & 3, hp = t >> 2;    // 64 h-pairs x 4 col-pairs
    #pragma unroll
    for (int q = 1; q <= 4; ++q) {        // h-bits 1..4 (angle[5..2])
        float a, s; gate_coeffs(angle[6 - q], a, s);
        int h0 = ((hp >> q) << (q + 1)) | (hp & ((1 << q) - 1));
        int i0 = sB(h0, cB), i1 = sB(h0 + (1 << q), cB);
        f4 v0 = lb[i0], v1 = lb[i1];
        bf(v0, v1, a, s);
        lb[i0] = v0; lb[i1] = v1;
        __syncthreads();
    }

    // h-bit 5 (angle[1]) in registers: stride-32 within 128-range needs the
    // insert-zero-at-bit-5 pairing, NOT (hp, hp+32).
    float a5, s5; gate_coeffs(angle[1], a5, s5);
    const int h0f = ((hp >> 5) << 6) | (hp & 31);    // h with bit 5 = 0
    f4 v0 = lb[sB(h0f, cB)], v1 = lb[sB(h0f + 32, cB)];
    bf(v0, v1, a5, s5);
    float2* outre2 = (float2*)out;
    float2* outim2 = (float2*)(out + PLANE);
    const int CP = oct * 4 + cB;
    const int r0 = h0f * 64 + m;          // partner row = r0 + 32*64
    outre2[r0 * 32 + CP]          = make_float2(v0.x, v0.z);
    outim2[r0 * 32 + CP]          = make_float2(v0.y, v0.w);
    outre2[(r0 + 2048) * 32 + CP] = make_float2(v1.x, v1.z);
    outim2[(r0 + 2048) * 32 + CP] = make_float2(v1.y, v1.w);
}

extern "C" void kernel_launch(void* const* d_in, const int* in_sizes, int n_in,
                              void* d_out, int out_size, void* d_ws, size_t ws_size,
                              hipStream_t stream) {
    const float* xr    = (const float*)d_in[0];
    const float* xi    = (const float*)d_in[1];
    const float* angle = (const float*)d_in[2];
    float* out = (float*)d_out;
    f4*    ws4 = (f4*)d_ws;            // 4 MB intermediate

    rx_low <<<512, 256, 0, stream>>>(xr, xi, angle, ws4);
    rx_high<<<512, 256, 0, stream>>>(angle, ws4, out);
}

// Round 9
// 13.707 us; speedup vs baseline: 11.3794x; 1.0747x over previous
//
#include <hip/hip_runtime.h>

// 8192 rows x 64 cols complex, separate re/im float planes; out = [2][8192][64].
// Row r = h*64 + m (h = r>>6, m = r&63). Gate angle[i] acts on row-bit (12-i);
// m-bit j <-> angle[12-j], h-bit j <-> angle[6-j]. Gates commute (distinct bits).
// Kernel A: m-bits. radix-4: bits {0,1} fused into global load (registers),
//   {2,3} one LDS round-trip, {4,5} fused into ws store. 2 barriers.
// Kernel B: h-bits. {5,6} fused into ws load, {3,4} and {1,2} LDS round-trips,
//   {0} fused into out store. 3 barriers.
// f4 = (re,im) x 2 adjacent cols. cp32 = col-pair 0..31; q = cp32>>3, cb = cp32&7.
// ws[(m*4+q)*1024 + h*8 + cb] = B's linear LDS order -> B loads 1KB/wave contiguous.
// LDS layouts keep the col-pair in the low 3 slot bits -> every strided access is
// exactly 8 lanes/bank-quad (the b128 floor); no swizzle required.
#define PLANE (8192 * 64)

typedef float f4 __attribute__((ext_vector_type(4)));

__device__ __forceinline__ void gate_coeffs(float theta, float& a, float& s) {
    // truncated series, CUTOFF=10: a ~ cos(theta/2) thru t^10, s ~ sin(theta/2) thru t^9
    float t = 0.5f * theta;
    float u = t * t;
    s = t * (1.f + u * (-1.f/6.f + u * (1.f/120.f + u * (-1.f/5040.f + u * (1.f/362880.f)))));
    a = 1.f + u * (-0.5f + u * (1.f/24.f + u * (-1.f/720.f + u * (1.f/40320.f + u * (-1.f/3628800.f)))));
}

// v = (reA, imA, reB, imB) for two cols of one row; RX pair update.
__device__ __forceinline__ void bf(f4& v0, f4& v1, float a, float s) {
    f4 n0, n1;
    n0.x = a * v0.x + s * v1.y;  n0.y = a * v0.y - s * v1.x;
    n0.z = a * v0.z + s * v1.w;  n0.w = a * v0.w - s * v1.z;
    n1.x = a * v1.x + s * v0.y;  n1.y = a * v1.y - s * v0.x;
    n1.z = a * v1.z + s * v0.w;  n1.w = a * v1.w - s * v0.z;
    v0 = n0; v1 = n1;
}

// Kernel A: m-bits 0..5. Block = rows g*64..+63 x 32 cols (16 col-pairs).
// grid = 128 g x 2 halves = 256 blocks x 256 threads. LDS [64 rows][16 cp] f4.
__global__ __launch_bounds__(256) void rx_low(const float* __restrict__ xr,
                                              const float* __restrict__ xi,
                                              const float* __restrict__ angle,
                                              f4* __restrict__ ws4) {
    __shared__ f4 l4[64 * 16];        // 16 KB
    const int t = threadIdx.x, bid = blockIdx.x;
    const int g = bid >> 1, half = bid & 1;
    const int cp = t & 15, rq = t >> 4;    // cp 0..15, row-quad 0..15

    const float2* xr2 = (const float2*)xr;
    const float2* xi2 = (const float2*)xi;

    // trip 1: global -> regs, bits 0,1 in registers, write LDS
    {
        float a0, s0, a1, s1;
        gate_coeffs(angle[12], a0, s0);            // m-bit 0
        gate_coeffs(angle[11], a1, s1);            // m-bit 1
        f4 v[4];
        #pragma unroll
        for (int k = 0; k < 4; ++k) {              // rows 4rq+k (bits 0,1 free)
            int gi = (g * 64 + 4 * rq + k) * 32 + half * 16 + cp;
            float2 re = xr2[gi], im = xi2[gi];
            v[k] = (f4){re.x, im.x, re.y, im.y};
        }
        bf(v[0], v[1], a0, s0); bf(v[2], v[3], a0, s0);
        bf(v[0], v[2], a1, s1); bf(v[1], v[3], a1, s1);
        #pragma unroll
        for (int k = 0; k < 4; ++k) l4[(4 * rq + k) * 16 + cp] = v[k];
    }
    __syncthreads();

    // trip 2: LDS round-trip, bits 2,3 (rows base+{0,4,8,12}; base bits 2,3 = 0)
    {
        float a2, s2, a3, s3;
        gate_coeffs(angle[10], a2, s2);            // m-bit 2
        gate_coeffs(angle[9],  a3, s3);            // m-bit 3
        int base = ((rq >> 2) << 4) | (rq & 3);
        f4 w0 = l4[(base     ) * 16 + cp], w1 = l4[(base +  4) * 16 + cp];
        f4 w2 = l4[(base +  8) * 16 + cp], w3 = l4[(base + 12) * 16 + cp];
        bf(w0, w1, a2, s2); bf(w2, w3, a2, s2);
        bf(w0, w2, a3, s3); bf(w1, w3, a3, s3);
        l4[(base     ) * 16 + cp] = w0; l4[(base +  4) * 16 + cp] = w1;
        l4[(base +  8) * 16 + cp] = w2; l4[(base + 12) * 16 + cp] = w3;
    }
    __syncthreads();

    // trip 3: LDS read, bits 4,5 in registers (rows rq+{0,16,32,48}), store ws
    {
        float a4, s4, a5, s5;
        gate_coeffs(angle[8], a4, s4);             // m-bit 4
        gate_coeffs(angle[7], a5, s5);             // m-bit 5
        f4 w0 = l4[(rq     ) * 16 + cp], w1 = l4[(rq + 16) * 16 + cp];
        f4 w2 = l4[(rq + 32) * 16 + cp], w3 = l4[(rq + 48) * 16 + cp];
        bf(w0, w1, a4, s4); bf(w2, w3, a4, s4);
        bf(w0, w2, a5, s5); bf(w1, w3, a5, s5);
        const int cp32 = half * 16 + cp, q = cp32 >> 3, cb = cp32 & 7;
        const int e = g * 8 + cb;
        ws4[(size_t)((rq     ) * 4 + q) * 1024 + e] = w0;   // m = rq
        ws4[(size_t)((rq + 16) * 4 + q) * 1024 + e] = w1;   // m = rq+16
        ws4[(size_t)((rq + 32) * 4 + q) * 1024 + e] = w2;   // m = rq+32
        ws4[(size_t)((rq + 48) * 4 + q) * 1024 + e] = w3;   // m = rq+48
    }
}

// Kernel B: h-bits 0..6. Block = m fixed x 16 cols (8 cp), h 0..127.
// grid = 64 m x 4 q = 256 blocks x 256 threads. LDS [128 h][8 cp] f4.
__global__ __launch_bounds__(256) void rx_high(const float* __restrict__ angle,
                                               const f4* __restrict__ ws4,
                                               float* __restrict__ out) {
    __shared__ f4 l4[128 * 8];        // 16 KB
    const int t = threadIdx.x, bid = blockIdx.x;
    const int m = bid >> 2, q = bid & 3;
    const int cp = t & 7, hq = t >> 3;     // cp 0..7, hq 0..31

    // trip 1: ws -> regs (1KB/wave contiguous), h-bits 5,6 in registers, write LDS
    {
        float a5, s5, a6, s6;
        gate_coeffs(angle[1], a5, s5);             // h-bit 5
        gate_coeffs(angle[0], a6, s6);             // h-bit 6
        const f4* src = ws4 + (size_t)(m * 4 + q) * 1024;
        f4 v0 = src[(hq     ) * 8 + cp], v1 = src[(hq + 32) * 8 + cp];
        f4 v2 = src[(hq + 64) * 8 + cp], v3 = src[(hq + 96) * 8 + cp];
        bf(v0, v1, a5, s5); bf(v2, v3, a5, s5);
        bf(v0, v2, a6, s6); bf(v1, v3, a6, s6);
        l4[(hq     ) * 8 + cp] = v0; l4[(hq + 32) * 8 + cp] = v1;
        l4[(hq + 64) * 8 + cp] = v2; l4[(hq + 96) * 8 + cp] = v3;
    }
    __syncthreads();

    // trip 2: LDS round-trip, h-bits 3,4 (h = base+{0,8,16,24}; base bits 3,4 = 0)
    {
        float a3, s3, a4, s4;
        gate_coeffs(angle[3], a3, s3);             // h-bit 3
        gate_coeffs(angle[2], a4, s4);             // h-bit 4
        int base = ((hq >> 3) << 5) | (hq & 7);
        f4 w0 = l4[(base     ) * 8 + cp], w1 = l4[(base +  8) * 8 + cp];
        f4 w2 = l4[(base + 16) * 8 + cp], w3 = l4[(base + 24) * 8 + cp];
        bf(w0, w1, a3, s3); bf(w2, w3, a3, s3);
        bf(w0, w2, a4, s4); bf(w1, w3, a4, s4);
        l4[(base     ) * 8 + cp] = w0; l4[(base +  8) * 8 + cp] = w1;
        l4[(base + 16) * 8 + cp] = w2; l4[(base + 24) * 8 + cp] = w3;
    }
    __syncthreads();

    // trip 3: LDS round-trip, h-bits 1,2 (h = b+{0,2,4,6}; b bits 1,2 = 0)
    {
        float a1, s1, a2, s2;
        gate_coeffs(angle[5], a1, s1);             // h-bit 1
        gate_coeffs(angle[4], a2, s2);             // h-bit 2
        int b = ((hq >> 1) << 3) | (hq & 1);
        f4 w0 = l4[(b    ) * 8 + cp], w1 = l4[(b + 2) * 8 + cp];
        f4 w2 = l4[(b + 4) * 8 + cp], w3 = l4[(b + 6) * 8 + cp];
        bf(w0, w1, a1, s1); bf(w2, w3, a1, s1);
        bf(w0, w2, a2, s2); bf(w1, w3, a2, s2);
        l4[(b    ) * 8 + cp] = w0; l4[(b + 2) * 8 + cp] = w1;
        l4[(b + 4) * 8 + cp] = w2; l4[(b + 6) * 8 + cp] = w3;
    }
    __syncthreads();

    // trip 4: LDS read, h-bit 0 in registers (pairs (2hp, 2hp+1)), store out
    {
        float a0, s0;
        gate_coeffs(angle[6], a0, s0);             // h-bit 0
        float2* outre2 = (float2*)out;
        float2* outim2 = (float2*)(out + PLANE);
        #pragma unroll
        for (int pp = 0; pp < 2; ++pp) {
            int hp = hq + 32 * pp;                 // 0..63
            f4 w0 = l4[(2 * hp) * 8 + cp], w1 = l4[(2 * hp + 1) * 8 + cp];
            bf(w0, w1, a0, s0);
            int o = ((2 * hp) * 64 + m) * 32 + q * 8 + cp;   // row 2hp*64+m
            outre2[o] = make_float2(w0.x, w0.z);
            outim2[o] = make_float2(w0.y, w0.w);
            outre2[o + 2048] = make_float2(w1.x, w1.z);      // row +64
            outim2[o + 2048] = make_float2(w1.y, w1.w);
        }
    }
}

extern "C" void kernel_launch(void* const* d_in, const int* in_sizes, int n_in,
                              void* d_out, int out_size, void* d_ws, size_t ws_size,
                              hipStream_t stream) {
    const float* xr    = (const float*)d_in[0];
    const float* xi    = (const float*)d_in[1];
    const float* angle = (const float*)d_in[2];
    float* out = (float*)d_out;
    f4*    ws4 = (f4*)d_ws;            // 4 MB intermediate

    rx_low <<<256, 256, 0, stream>>>(xr, xi, angle, ws4);
    rx_high<<<256, 256, 0, stream>>>(angle, ws4, out);
}